// Round 8
// baseline (112.622 us; speedup 1.0000x reference)
//
#include <hip/hip_runtime.h>

// Problem constants: m=4, h=16, t=1024, d=128, MAX_REL=128.
constexpr int D_DIM = 128;
constexpr int T_Q   = 1024;
constexpr int NPE   = 257;               // 2*MAX_REL + 1 pe rows
constexpr int WAVES = 16;                // 1024-thread block -> 4 waves/SIMD
constexpr int BLOCK_THREADS  = WAVES * 64;
constexpr int ROWS_PER_WAVE  = 16;
constexpr int ROWS_PER_BLOCK = WAVES * ROWS_PER_WAVE;   // 256; grid = 256 = 1 block/CU

// readlane: uniform lane index (SGPR), static register -> SGPR broadcast, no DS/memory.
#define RL(V, SRC) __uint_as_float(__builtin_amdgcn_readlane(__float_as_uint(V), (SRC)))

// pe row j element d at pe_lds[j*128 + ((d + 4*j) & 127)]:
// lane l owns j in {l, l+64, l+128, l+192}; 4*j mod 128 equal for all four, so one
// physical column po=(4*sd+4l)&127 serves all 4 ds_read_b128. Lanes 0..7 tile all
// 32 banks -> conflict-free; po multiple of 4, <=124 -> float4 never wraps.
//
// Q burst layout: RPW rows x 128 dims, CH=RPW/2 float4 chunks/lane; chunk c lane l
// holds flat floats [c*256 + 4l .. +3] = row 2c+(l>=32), dims 4(l&31)..+3.
// q[row r][dim 4sd+i] = chunk r>>1, source lane 32*(r&1)+sd, component i.
template<int RPW>
__device__ __forceinline__ void wave_work(const float* __restrict__ Q,
                                          float* __restrict__ out,
                                          const float (&pe_lds)[NPE * 128],
                                          float (&scratch)[256],
                                          const int waveRow0, const int l)
{
    constexpr int NIT = ROWS_PER_WAVE / RPW;   // 2 (RPW=8) or 4 (RPW=4)
    constexpr int CH  = RPW / 2;

    // ---- ALL Q bursts up-front: zero vmem loads after the first store, so no
    //      compiler waitcnt ever needs to drain the store queue mid-kernel. ----
    float4 qb[NIT][CH];
#pragma unroll
    for (int i = 0; i < NIT; ++i) {
        const float* qsrc = Q + (size_t)(waveRow0 + i * RPW) * D_DIM;
#pragma unroll
        for (int c = 0; c < CH; ++c)
            qb[i][c] = *reinterpret_cast<const float4*>(qsrc + c * 256 + 4 * l);
    }

#pragma unroll
    for (int i = 0; i < NIT; ++i) {
        const int gRow0 = waveRow0 + i * RPW;

        float acc[RPW][4];
#pragma unroll
        for (int r = 0; r < RPW; ++r) {
            acc[r][0] = 0.f; acc[r][1] = 0.f; acc[r][2] = 0.f; acc[r][3] = 0.f;
        }

        // ---- main loop: 32 steps of 4 dims; acc[r][k] = dot(q_r, pe_{l+64k}) ----
#pragma unroll 2
        for (int sd = 0; sd < 32; ++sd) {
            const int po = (4 * sd + 4 * l) & 127;
            const float4 p0 = *reinterpret_cast<const float4*>(&pe_lds[(l      ) * 128 + po]);
            const float4 p1 = *reinterpret_cast<const float4*>(&pe_lds[(l +  64) * 128 + po]);
            const float4 p2 = *reinterpret_cast<const float4*>(&pe_lds[(l + 128) * 128 + po]);
            const float4 p3 = *reinterpret_cast<const float4*>(&pe_lds[(l + 192) * 128 + po]);
#pragma unroll
            for (int r = 0; r < RPW; ++r) {
                const int src = ((r & 1) << 5) + sd;
                const float qx = RL(qb[i][r >> 1].x, src);
                const float qy = RL(qb[i][r >> 1].y, src);
                const float qz = RL(qb[i][r >> 1].z, src);
                const float qw = RL(qb[i][r >> 1].w, src);
                acc[r][0] = fmaf(qx, p0.x, acc[r][0]);
                acc[r][1] = fmaf(qx, p1.x, acc[r][1]);
                acc[r][2] = fmaf(qx, p2.x, acc[r][2]);
                acc[r][3] = fmaf(qx, p3.x, acc[r][3]);
                acc[r][0] = fmaf(qy, p0.y, acc[r][0]);
                acc[r][1] = fmaf(qy, p1.y, acc[r][1]);
                acc[r][2] = fmaf(qy, p2.y, acc[r][2]);
                acc[r][3] = fmaf(qy, p3.y, acc[r][3]);
                acc[r][0] = fmaf(qz, p0.z, acc[r][0]);
                acc[r][1] = fmaf(qz, p1.z, acc[r][1]);
                acc[r][2] = fmaf(qz, p2.z, acc[r][2]);
                acc[r][3] = fmaf(qz, p3.z, acc[r][3]);
                acc[r][0] = fmaf(qw, p0.w, acc[r][0]);
                acc[r][1] = fmaf(qw, p1.w, acc[r][1]);
                acc[r][2] = fmaf(qw, p2.w, acc[r][2]);
                acc[r][3] = fmaf(qw, p3.w, acc[r][3]);
            }
        }

        // ---- rel[256] per row from burst registers (no global reads):
        //      lane partial over its 4 dims, butterfly within 32-lane halves,
        //      xor-32 swap to get both halves' rows everywhere. ----
        float rel256[RPW];
        {
            // row 256 rotation: (4*256)&127==0 -> unrotated; dims 4(l&31)..+3
            const float4 pr = *reinterpret_cast<const float4*>(&pe_lds[256 * 128 + 4 * (l & 31)]);
            const bool hi = (l >= 32);
#pragma unroll
            for (int c = 0; c < CH; ++c) {
                float p = qb[i][c].x * pr.x + qb[i][c].y * pr.y
                        + qb[i][c].z * pr.z + qb[i][c].w * pr.w;
#pragma unroll
                for (int off = 16; off; off >>= 1)
                    p += __shfl_xor(p, off, 64);      // reduce within each 32-lane half
                const float q2 = __shfl_xor(p, 32, 64); // other half's row sum
                rel256[2 * c]     = hi ? q2 : p;       // row 2c   lives in low half
                rel256[2 * c + 1] = hi ? p  : q2;      // row 2c+1 lives in high half
            }
        }

        // ---- epilogue: spill window, region-split gather, coalesced b128 stores
        //      (stores are fire-and-forget; nothing ever waits on them). ----
#pragma unroll 1
        for (int r = 0; r < RPW; ++r) {
            scratch[l      ] = acc[r][0];     // window j = l + 64k
            scratch[l +  64] = acc[r][1];
            scratch[l + 128] = acc[r][2];
            scratch[l + 192] = acc[r][3];
            asm volatile("s_waitcnt lgkmcnt(0)" ::: "memory");

            const int gRow = gRow0 + r;
            const int t = gRow & (T_Q - 1);
            float* orow = out + (size_t)gRow * T_Q;
            const float r256 = rel256[r];
            const float r0   = __builtin_amdgcn_readfirstlane(acc[r][0]); // rel[j=0]

#pragma unroll
            for (int k = 0; k < 4; ++k) {
                const int s0 = 4 * l + 256 * k;
                const int j0 = t + 128 - s0;          // jraw at c=0 (group max)
                float4 v;
                if (j0 <= 0) {                         // all right-clipped -> rel[0]
                    v = make_float4(r0, r0, r0, r0);
                } else if (j0 >= 259) {                // all left-clipped -> rel[256]
                    v = make_float4(r256, r256, r256, r256);
                } else {                               // reversed window gather
                    float x[4];
#pragma unroll
                    for (int c = 0; c < 4; ++c) {
                        const int jr = j0 - c;
                        const int jc = jr < 0 ? 0 : (jr > 255 ? 255 : jr);
                        const float sv = scratch[jc];
                        x[c] = (jr >= 256) ? r256 : ((jr <= 0) ? r0 : sv);
                    }
                    v = make_float4(x[0], x[1], x[2], x[3]);
                }
                reinterpret_cast<float4*>(orow)[l + 64 * k] = v;
            }
            // DS pipe is in-order per wave: next r's scratch writes cannot pass
            // this r's gather reads (lgkm-waited before the dependent stores).
        }
    }
}

// LDS: pe (rotated) 131.6 KB + per-wave rel scratch 16 KB = 147.6 KB -> 1 block/CU,
// 16 waves = 4 waves/SIMD.
__global__ __launch_bounds__(BLOCK_THREADS, 4)   // <=128 VGPR; need ~110
void rpe_fused(const float* __restrict__ Q,
               const float* __restrict__ pe,
               float* __restrict__ out)
{
    __shared__ float pe_lds[NPE * 128];
    __shared__ float scratch[WAVES][256];

    const int tid = threadIdx.x;
    const int w   = tid >> 6;
    const int l   = tid & 63;

    // ---- stage pe into LDS with rotation (once per block) ----
    for (int flat = tid; flat < NPE * 128; flat += BLOCK_THREADS) {
        const int r = flat >> 7;
        const int d = flat & 127;
        pe_lds[r * 128 + ((d + 4 * r) & 127)] = pe[flat];
    }
    __syncthreads();

    const int waveRow0 = blockIdx.x * ROWS_PER_BLOCK + w * ROWS_PER_WAVE;

    // Mixed-cadence stagger: even waves 2x(compute8+store8), odd waves
    // 4x(compute4+store4) -> VALU phases of some waves overlap store phases
    // of others instead of the whole SIMD phase-locking.
    if (w & 1) wave_work<4>(Q, out, pe_lds, scratch[w], waveRow0, l);
    else       wave_work<8>(Q, out, pe_lds, scratch[w], waveRow0, l);
}

extern "C" void kernel_launch(void* const* d_in, const int* in_sizes, int n_in,
                              void* d_out, int out_size, void* d_ws, size_t ws_size,
                              hipStream_t stream)
{
    const float* Q  = (const float*)d_in[0];
    // d_in[1] is K: only its shape matters (t_k = 1024), data unused.
    const float* pe = (const float*)d_in[2];
    float* out = (float*)d_out;

    const int total_rows = in_sizes[0] / D_DIM;        // m*h*t = 65536
    const int grid = total_rows / ROWS_PER_BLOCK;      // 256 -> one block per CU
    rpe_fused<<<grid, BLOCK_THREADS, 0, stream>>>(Q, pe, out);
}

// Round 9
// 109.724 us; speedup vs baseline: 1.0264x; 1.0264x over previous
//
#include <hip/hip_runtime.h>

// Problem constants: m=4, h=16, t=1024, d=128, MAX_REL=128.
constexpr int D_DIM = 128;
constexpr int T_Q   = 1024;
constexpr int NPE   = 257;               // 2*MAX_REL + 1 pe rows
constexpr int WAVES = 16;                // 1024-thread block -> 4 waves/SIMD
constexpr int RPW   = 8;                 // rows per wave per iteration
constexpr int BLOCK_THREADS  = WAVES * 64;
constexpr int ROWS_PER_WAVE  = 16;       // 2 iterations of RPW=8
constexpr int ROWS_PER_BLOCK = WAVES * ROWS_PER_WAVE;   // 256; grid = 256 = 1 block/CU

// readlane: uniform lane index (SGPR), static register -> SGPR broadcast, no DS/memory.
#define RL(V, SRC) __uint_as_float(__builtin_amdgcn_readlane(__float_as_uint(V), (SRC)))

// pe row j element d at pe_lds[j*128 + ((d + 4*j) & 127)]:
// lane l owns j in {l, l+64, l+128, l+192}; 4*j mod 128 equal for all four, so one
// physical column po=(4*sd+4l)&127 serves all 4 ds_read_b128. Lanes 0..7 tile all
// 32 banks -> conflict-free; po multiple of 4, <=124 -> float4 never wraps.
#define LOAD_P(BUF, STEP) {                                                        \
    const int po_ = (((STEP) * 4 + 4 * l) & 127);                                  \
    BUF[0] = *reinterpret_cast<const float4*>(&pe_lds[(l      ) * 128 + po_]);     \
    BUF[1] = *reinterpret_cast<const float4*>(&pe_lds[(l +  64) * 128 + po_]);     \
    BUF[2] = *reinterpret_cast<const float4*>(&pe_lds[(l + 128) * 128 + po_]);     \
    BUF[3] = *reinterpret_cast<const float4*>(&pe_lds[(l + 192) * 128 + po_]);     \
}

// One 4-dim step for 8 rows: 32 readlane + 128 FMA = 160 VALU.
// Q burst: chunk c lane l holds row 2c+(l>=32), dims 4(l&31)..+3;
// q[row r][dim 4*SD+i] = chunk r>>1, source lane 32*(r&1)+SD, component i.
#define FMA_STEP(QB, SD, PB) {                                                     \
    _Pragma("unroll")                                                              \
    for (int r_ = 0; r_ < RPW; ++r_) {                                             \
        const int src_ = ((r_ & 1) << 5) + (SD);                                   \
        const float qx = RL(QB[r_ >> 1].x, src_);                                  \
        const float qy = RL(QB[r_ >> 1].y, src_);                                  \
        const float qz = RL(QB[r_ >> 1].z, src_);                                  \
        const float qw = RL(QB[r_ >> 1].w, src_);                                  \
        acc[r_][0] = fmaf(qx, PB[0].x, acc[r_][0]);                                \
        acc[r_][1] = fmaf(qx, PB[1].x, acc[r_][1]);                                \
        acc[r_][2] = fmaf(qx, PB[2].x, acc[r_][2]);                                \
        acc[r_][3] = fmaf(qx, PB[3].x, acc[r_][3]);                                \
        acc[r_][0] = fmaf(qy, PB[0].y, acc[r_][0]);                                \
        acc[r_][1] = fmaf(qy, PB[1].y, acc[r_][1]);                                \
        acc[r_][2] = fmaf(qy, PB[2].y, acc[r_][2]);                                \
        acc[r_][3] = fmaf(qy, PB[3].y, acc[r_][3]);                                \
        acc[r_][0] = fmaf(qz, PB[0].z, acc[r_][0]);                                \
        acc[r_][1] = fmaf(qz, PB[1].z, acc[r_][1]);                                \
        acc[r_][2] = fmaf(qz, PB[2].z, acc[r_][2]);                                \
        acc[r_][3] = fmaf(qz, PB[3].z, acc[r_][3]);                                \
        acc[r_][0] = fmaf(qw, PB[0].w, acc[r_][0]);                                \
        acc[r_][1] = fmaf(qw, PB[1].w, acc[r_][1]);                                \
        acc[r_][2] = fmaf(qw, PB[2].w, acc[r_][2]);                                \
        acc[r_][3] = fmaf(qw, PB[3].w, acc[r_][3]);                                \
    }                                                                              \
}

// LDS: pe (rotated) 131.6 KB + per-wave rel scratch 16 KB = 147.6 KB -> 1 block/CU,
// 16 waves = 4 waves/SIMD.
__global__ __launch_bounds__(BLOCK_THREADS, 4)   // <=128 VGPR; need ~120
void rpe_fused(const float* __restrict__ Q,
               const float* __restrict__ pe,
               float* __restrict__ out)
{
    __shared__ float pe_lds[NPE * 128];
    __shared__ float scratch[WAVES][256];

    const int tid = threadIdx.x;
    const int w   = tid >> 6;
    const int l   = tid & 63;

    // ---- stage pe into LDS with rotation (once per block) ----
    for (int flat = tid; flat < NPE * 128; flat += BLOCK_THREADS) {
        const int r = flat >> 7;
        const int d = flat & 127;
        pe_lds[r * 128 + ((d + 4 * r) & 127)] = pe[flat];
    }
    __syncthreads();

    const int waveRow0 = blockIdx.x * ROWS_PER_BLOCK + w * ROWS_PER_WAVE;

    // ---- ALL Q bursts up-front (coalesced, 32 VGPR): zero vmem loads after the
    //      first store -> no waitcnt can ever drain the store queue mid-kernel. ----
    float4 qb[2][4];
#pragma unroll
    for (int i = 0; i < 2; ++i) {
        const float* qsrc = Q + (size_t)(waveRow0 + i * RPW) * D_DIM;
#pragma unroll
        for (int c = 0; c < 4; ++c)
            qb[i][c] = *reinterpret_cast<const float4*>(qsrc + c * 256 + 4 * l);
    }

#pragma unroll
    for (int i = 0; i < 2; ++i) {
        const int gRow0 = waveRow0 + i * RPW;

        float acc[RPW][4];
#pragma unroll
        for (int r = 0; r < RPW; ++r) {
            acc[r][0] = 0.f; acc[r][1] = 0.f; acc[r][2] = 0.f; acc[r][3] = 0.f;
        }

        // ---- main loop: A/B ping-pong of pe reads, pinned by sched_group_barrier
        //      so step k+1's 4 ds_read_b128 issue BEFORE step k's 160 VALU ops.
        //      Backend then emits counted lgkmcnt(4): DS latency hides under FMA. ----
        float4 pA[4], pB[4];
        LOAD_P(pA, 0)
#pragma unroll 1
        for (int s2 = 0; s2 < 16; ++s2) {
            const int s0 = 2 * s2;
            const int s1 = 2 * s2 + 1;
            const int sn = (2 * s2 + 2) & 31;      // wraps to 0 on last iter (dead, in-bounds)
            LOAD_P(pB, s1)
            FMA_STEP(qb[i], s0, pA)                // covers pB's in-flight latency
            LOAD_P(pA, sn)
            FMA_STEP(qb[i], s1, pB)                // covers pA's in-flight latency
            // scheduling pattern for this body (in order):
            __builtin_amdgcn_sched_group_barrier(0x002, 12, 0);   // addr VALU
            __builtin_amdgcn_sched_group_barrier(0x100,  4, 0);   // pB ds_read_b128 x4
            __builtin_amdgcn_sched_group_barrier(0x002, 160, 0);  // FMA_STEP(pA)
            __builtin_amdgcn_sched_group_barrier(0x002, 12, 0);   // addr VALU
            __builtin_amdgcn_sched_group_barrier(0x100,  4, 0);   // pA ds_read_b128 x4
            __builtin_amdgcn_sched_group_barrier(0x002, 160, 0);  // FMA_STEP(pB)
        }

        // ---- rel[256] per row from burst registers (no global reads):
        //      lane partial over its 4 dims, butterfly within 32-lane halves,
        //      xor-32 swap to get both halves' rows everywhere. ----
        float rel256[RPW];
        {
            // row 256 rotation: (4*256)&127==0 -> unrotated; dims 4(l&31)..+3
            const float4 pr = *reinterpret_cast<const float4*>(&pe_lds[256 * 128 + 4 * (l & 31)]);
            const bool hi = (l >= 32);
#pragma unroll
            for (int c = 0; c < 4; ++c) {
                float p = qb[i][c].x * pr.x + qb[i][c].y * pr.y
                        + qb[i][c].z * pr.z + qb[i][c].w * pr.w;
#pragma unroll
                for (int off = 16; off; off >>= 1)
                    p += __shfl_xor(p, off, 64);      // reduce within each 32-lane half
                const float q2 = __shfl_xor(p, 32, 64); // other half's row sum
                rel256[2 * c]     = hi ? q2 : p;       // row 2c   lives in low half
                rel256[2 * c + 1] = hi ? p  : q2;      // row 2c+1 lives in high half
            }
        }

        // ---- epilogue: spill window, region-split gather, coalesced b128 stores.
        //      No explicit lgkm drain: the DS pipe is in-order per wave, so the
        //      gather reads (issued after the writes, may-alias -> compiler keeps
        //      order) observe the writes; only data-arrival waits are needed and
        //      the compiler inserts those. Stores are fire-and-forget. ----
#pragma unroll 1
        for (int r = 0; r < RPW; ++r) {
            scratch[w][l      ] = acc[r][0];     // window j = l + 64k
            scratch[w][l +  64] = acc[r][1];
            scratch[w][l + 128] = acc[r][2];
            scratch[w][l + 192] = acc[r][3];

            const int gRow = gRow0 + r;
            const int t = gRow & (T_Q - 1);
            float* orow = out + (size_t)gRow * T_Q;
            const float r256 = rel256[r];
            const float r0   = __builtin_amdgcn_readfirstlane(acc[r][0]); // rel[j=0]

#pragma unroll
            for (int k = 0; k < 4; ++k) {
                const int s0 = 4 * l + 256 * k;
                const int j0 = t + 128 - s0;          // jraw at c=0 (group max)
                float4 v;
                if (j0 <= 0) {                         // all right-clipped -> rel[0]
                    v = make_float4(r0, r0, r0, r0);
                } else if (j0 >= 259) {                // all left-clipped -> rel[256]
                    v = make_float4(r256, r256, r256, r256);
                } else {                               // reversed window gather
                    float x[4];
#pragma unroll
                    for (int c = 0; c < 4; ++c) {
                        const int jr = j0 - c;
                        const int jc = jr < 0 ? 0 : (jr > 255 ? 255 : jr);
                        const float sv = scratch[w][jc];
                        x[c] = (jr >= 256) ? r256 : ((jr <= 0) ? r0 : sv);
                    }
                    v = make_float4(x[0], x[1], x[2], x[3]);
                }
                reinterpret_cast<float4*>(orow)[l + 64 * k] = v;
            }
            // next r's scratch writes cannot pass this r's gather reads (DS in-order,
            // may-alias ordering preserved by the compiler).
        }
    }
}

extern "C" void kernel_launch(void* const* d_in, const int* in_sizes, int n_in,
                              void* d_out, int out_size, void* d_ws, size_t ws_size,
                              hipStream_t stream)
{
    const float* Q  = (const float*)d_in[0];
    // d_in[1] is K: only its shape matters (t_k = 1024), data unused.
    const float* pe = (const float*)d_in[2];
    float* out = (float*)d_out;

    const int total_rows = in_sizes[0] / D_DIM;        // m*h*t = 65536
    const int grid = total_rows / ROWS_PER_BLOCK;      // 256 -> one block per CU
    rpe_fused<<<grid, BLOCK_THREADS, 0, stream>>>(Q, pe, out);
}

// Round 10
// 87.637 us; speedup vs baseline: 1.2851x; 1.2520x over previous
//
#include <hip/hip_runtime.h>

// Problem constants: m=4, h=16, t=1024, d=128, MAX_REL=128.
constexpr int D_DIM = 128;
constexpr int T_Q   = 1024;
constexpr int NPE   = 257;               // 2*MAX_REL + 1 pe rows
constexpr int WAVES = 16;                // 1024-thread block -> 4 waves/SIMD
constexpr int BLOCK_THREADS  = WAVES * 64;
constexpr int ROWS_PER_WAVE  = 16;       // one 16-row MFMA M-tile per wave
constexpr int ROWS_PER_BLOCK = WAVES * ROWS_PER_WAVE;   // 256; grid 256 = 1 block/CU

typedef __attribute__((ext_vector_type(8))) short short8;  // bf16x8 MFMA operand
typedef __attribute__((ext_vector_type(4))) float f32x4;   // MFMA accumulator

// readlane: uniform lane index -> SGPR broadcast, no DS/memory.
#define RL(V, SRC) __uint_as_float(__builtin_amdgcn_readlane(__float_as_uint(V), (SRC)))

// Window GEMM per wave: D[16 rows][256 pe-rows] = Q_tile . pe^T, K=128.
// fp32 accuracy via hi/lo bf16 split: q = hi + lo (truncation split, residual
// exact in fp32); D = hi.hi + lo.hi + hi.lo, dropping lo.lo (<= ~2e-3 abs).
// Layout contract used (k-permutation-invariant): A row m = lane&15,
// B col n = lane&15; both operands place k-dims {32kk + 8g + e} (g=lane>>4,
// e=0..7) in the same slots, so any HW k-ordering cancels between A and B.
// C/D (HW-verified m89): col = lane&15, row = (lane>>4)*4 + reg.
//
// LDS: phi/plo bf16 [257][128] rotated (+8*(n&15) dims, mod 128) = 131.6 KB
//      + per-wave window scratch 16 KB = 147.6 KB -> 1 block/CU, 4 waves/SIMD.
__global__ __launch_bounds__(BLOCK_THREADS, 4)
void rpe_mfma(const float* __restrict__ Q,
              const float* __restrict__ pe,
              float* __restrict__ out)
{
    __shared__ ushort phi[NPE * 128];
    __shared__ ushort plo[NPE * 128];
    __shared__ float  scratch[WAVES][256];

    const int tid = threadIdx.x;
    const int w   = tid >> 6;
    const int l   = tid & 63;
    const int n15 = l & 15;
    const int g   = l >> 4;

    // ---- stage pe -> LDS as bf16 hi/lo, per-row rotation for conflict-free
    //      b128 fragment reads (start = ((32kk+8g)+8n)&127: multiple of 8,
    //      <=120 -> never wraps; lanes tile banks at minimum phases). ----
    for (int flat = tid; flat < NPE * 128; flat += BLOCK_THREADS) {
        const int n = flat >> 7;
        const int d = flat & 127;
        const float f  = pe[flat];
        const uint  u  = __float_as_uint(f);
        const float fl = f - __uint_as_float(u & 0xffff0000u);   // exact residual
        const int posr = (d + 8 * (n & 15)) & 127;
        phi[n * 128 + posr] = (ushort)(u >> 16);
        plo[n * 128 + posr] = (ushort)(__float_as_uint(fl) >> 16);
    }
    __syncthreads();

    const int waveRow0 = blockIdx.x * ROWS_PER_BLOCK + w * ROWS_PER_WAVE;

    // ---- A-fragments: lane holds row (waveRow0 + n15), dims 32kk+8g..+7 per kk.
    //      Coalesced: 4 lanes per row cover 128 contiguous bytes per kk. ----
    const float* qrow = Q + (size_t)(waveRow0 + n15) * D_DIM;
    short8 ahi[4], alo[4];
#pragma unroll
    for (int kk = 0; kk < 4; ++kk) {
        const int base = 32 * kk + 8 * g;
        const float4 a0 = *reinterpret_cast<const float4*>(qrow + base);
        const float4 a1 = *reinterpret_cast<const float4*>(qrow + base + 4);
        const float av[8] = {a0.x, a0.y, a0.z, a0.w, a1.x, a1.y, a1.z, a1.w};
#pragma unroll
        for (int e = 0; e < 8; ++e) {
            const uint u = __float_as_uint(av[e]);
            ahi[kk][e] = (short)(u >> 16);
            const float fl = av[e] - __uint_as_float(u & 0xffff0000u);
            alo[kk][e] = (short)(__float_as_uint(fl) >> 16);
        }
    }

    // ---- MFMA main: 16 n-tiles x 4 k-steps x 3 passes = 192 MFMA/wave. ----
    f32x4 acc[16];
#pragma unroll
    for (int j = 0; j < 16; ++j) acc[j] = (f32x4){0.f, 0.f, 0.f, 0.f};

#pragma unroll
    for (int kk = 0; kk < 4; ++kk) {
        const int posr = ((32 * kk + 8 * g) + 8 * n15) & 127;
#pragma unroll
        for (int j = 0; j < 16; ++j) {
            const int idx = (16 * j + n15) * 128 + posr;
            const short8 bh = *reinterpret_cast<const short8*>(&phi[idx]);
            const short8 bl = *reinterpret_cast<const short8*>(&plo[idx]);
            acc[j] = __builtin_amdgcn_mfma_f32_16x16x32_bf16(ahi[kk], bh, acc[j], 0, 0, 0);
            acc[j] = __builtin_amdgcn_mfma_f32_16x16x32_bf16(alo[kk], bh, acc[j], 0, 0, 0);
            acc[j] = __builtin_amdgcn_mfma_f32_16x16x32_bf16(ahi[kk], bl, acc[j], 0, 0, 0);
        }
    }

    // ---- rel[256] per row from the A-fragments + pe row 256 (rotation 0):
    //      lane partial over its 32 dims of row n15, then xor16+xor32 combines
    //      the four g-groups -> lane l holds rel256 of row (l&15). ----
    float rel_part = 0.f;
#pragma unroll
    for (int kk = 0; kk < 4; ++kk) {
        const int p2 = 256 * 128 + 32 * kk + 8 * g;     // (256&15)=0 -> unrotated
        const short8 ph = *reinterpret_cast<const short8*>(&phi[p2]);
        const short8 pl = *reinterpret_cast<const short8*>(&plo[p2]);
#pragma unroll
        for (int e = 0; e < 8; ++e) {
            const float qv = __uint_as_float(((uint)(ushort)ahi[kk][e]) << 16)
                           + __uint_as_float(((uint)(ushort)alo[kk][e]) << 16);
            const float pv = __uint_as_float(((uint)(ushort)ph[e]) << 16)
                           + __uint_as_float(((uint)(ushort)pl[e]) << 16);
            rel_part = fmaf(qv, pv, rel_part);
        }
    }
    rel_part += __shfl_xor(rel_part, 16, 64);
    rel_part += __shfl_xor(rel_part, 32, 64);

    // ---- epilogue, fully unrolled over the 16 rows (static acc indices):
    //      spill row r's window (16 lanes with g==r>>2 write 16 tiles each),
    //      then region-split gather + coalesced b128 stores (fire-and-forget;
    //      no vmem loads remain -> no store-queue drains). ----
#pragma unroll
    for (int r = 0; r < 16; ++r) {
        if (g == (r >> 2)) {
#pragma unroll
            for (int j = 0; j < 16; ++j)
                scratch[w][16 * j + n15] = acc[j][r & 3];   // banks 16(j&1)+n15: conflict-free
        }
        asm volatile("s_waitcnt lgkmcnt(0)" ::: "memory");

        const int gRow = waveRow0 + r;
        const int t = gRow & (T_Q - 1);
        float* orow = out + (size_t)gRow * T_Q;
        const float r256 = RL(rel_part, r);                  // lane r: row r's rel256
        const float r0   = RL(acc[0][r & 3], 16 * (r >> 2)); // win[0]: col 0, row r

#pragma unroll
        for (int k = 0; k < 4; ++k) {
            const int s0 = 4 * l + 256 * k;
            const int j0 = t + 128 - s0;          // jraw at c=0 (group max)
            float4 v;
            if (j0 <= 0) {                         // all right-clipped -> rel[0]
                v = make_float4(r0, r0, r0, r0);
            } else if (j0 >= 259) {                // all left-clipped -> rel[256]
                v = make_float4(r256, r256, r256, r256);
            } else {                               // reversed window gather
                float x[4];
#pragma unroll
                for (int c = 0; c < 4; ++c) {
                    const int jr = j0 - c;
                    const int jc = jr < 0 ? 0 : (jr > 255 ? 255 : jr);
                    const float sv = scratch[w][jc];
                    x[c] = (jr >= 256) ? r256 : ((jr <= 0) ? r0 : sv);
                }
                v = make_float4(x[0], x[1], x[2], x[3]);
            }
            reinterpret_cast<float4*>(orow)[l + 64 * k] = v;
        }
        // DS in-order per wave + may-alias: next r's scratch writes cannot pass
        // this r's gather reads.
    }
}

extern "C" void kernel_launch(void* const* d_in, const int* in_sizes, int n_in,
                              void* d_out, int out_size, void* d_ws, size_t ws_size,
                              hipStream_t stream)
{
    const float* Q  = (const float*)d_in[0];
    // d_in[1] is K: only its shape matters (t_k = 1024), data unused.
    const float* pe = (const float*)d_in[2];
    float* out = (float*)d_out;

    const int total_rows = in_sizes[0] / D_DIM;        // m*h*t = 65536
    const int grid = total_rows / ROWS_PER_BLOCK;      // 256 -> one block per CU
    rpe_mfma<<<grid, BLOCK_THREADS, 0, stream>>>(Q, pe, out);
}

// Round 11
// 81.937 us; speedup vs baseline: 1.3745x; 1.0696x over previous
//
#include <hip/hip_runtime.h>

// Problem constants: m=4, h=16, t=1024, d=128, MAX_REL=128.
constexpr int D_DIM = 128;
constexpr int T_Q   = 1024;
constexpr int NPE   = 257;               // 2*MAX_REL + 1 pe rows
constexpr int WAVES = 16;                // 1024-thread block -> 4 waves/SIMD
constexpr int BLOCK_THREADS  = WAVES * 64;
constexpr int ROWS_PER_WAVE  = 16;       // one 16-row MFMA M-tile per wave
constexpr int ROWS_PER_BLOCK = WAVES * ROWS_PER_WAVE;   // 256; grid 256 = 1 block/CU

typedef __attribute__((ext_vector_type(8))) short short8;  // bf16x8 MFMA operand
typedef __attribute__((ext_vector_type(4))) float f32x4;   // MFMA accumulator

// readlane: uniform lane index -> SGPR broadcast, no DS/memory.
#define RL(V, SRC) __uint_as_float(__builtin_amdgcn_readlane(__float_as_uint(V), (SRC)))

// Window GEMM per wave: D[16 rows][257 pe-rows] = Q_tile . pe^T, K=128.
// Precision: pe -> bf16 RNE (err <= 2^-9 rel); q -> hi + lo (truncation split),
// 2 MFMA passes (hi.b + lo.b). Net max error ~0.1 abs vs threshold 1.235.
// Layout contract (k-permutation-invariant, see round-9/10 notes):
// A row m = lane&15, B col n = lane&15, k-dims {32kk+8g+e} in matching slots.
// C/D (HW-verified m89): col = lane&15, row = (lane>>4)*4 + reg.
//
// Epilogue: per row, window stored REVERSED with shift c = row&3 into
// rev[u][p]: p = 256 - j + c for win[j]; pads p in [0,c] = win[256] (left-clip)
// and p in [257+c, 263] = win[0] (right-clip). Then out[s0..s0+3] is ONE
// aligned ds_read_b128 at p0 = s0 + (128 - t + c)  (p0 === 0 mod 4 since
// t === c mod 4), valid for 1 <= j0 <= 258; far-clip groups splat r0/r256.
//
// LDS: phi bf16 [257][128] rotated = 65.8 KB + rev [16][4][264] f32 = 67.6 KB
//      -> 133.4 KB, 1 block/CU, 4 waves/SIMD.
__global__ __launch_bounds__(BLOCK_THREADS, 4)
void rpe_mfma(const float* __restrict__ Q,
              const float* __restrict__ pe,
              float* __restrict__ out)
{
    __shared__ ushort phi[NPE * 128];
    __shared__ float  rev[WAVES][4][264];

    const int tid = threadIdx.x;
    const int w   = tid >> 6;
    const int l   = tid & 63;
    const int n15 = l & 15;
    const int g   = l >> 4;

    // ---- stage pe -> LDS as bf16 (RNE), rotated +8*(n&15) dims for
    //      conflict-free b128 fragment reads (never wraps a fragment). ----
    for (int flat = tid; flat < NPE * 128; flat += BLOCK_THREADS) {
        const int n = flat >> 7;
        const int d = flat & 127;
        const uint u = __float_as_uint(pe[flat]);
        const uint r = u + 0x7FFFu + ((u >> 16) & 1u);      // RNE to bf16
        phi[n * 128 + ((d + 8 * (n & 15)) & 127)] = (ushort)(r >> 16);
    }
    __syncthreads();

    const int waveRow0 = blockIdx.x * ROWS_PER_BLOCK + w * ROWS_PER_WAVE;

    // ---- A-fragments: lane holds row (waveRow0 + n15), dims 32kk+8g..+7. ----
    const float* qrow = Q + (size_t)(waveRow0 + n15) * D_DIM;
    short8 ahi[4], alo[4];
#pragma unroll
    for (int kk = 0; kk < 4; ++kk) {
        const int base = 32 * kk + 8 * g;
        const float4 a0 = *reinterpret_cast<const float4*>(qrow + base);
        const float4 a1 = *reinterpret_cast<const float4*>(qrow + base + 4);
        const float av[8] = {a0.x, a0.y, a0.z, a0.w, a1.x, a1.y, a1.z, a1.w};
#pragma unroll
        for (int e = 0; e < 8; ++e) {
            const uint u = __float_as_uint(av[e]);
            ahi[kk][e] = (short)(u >> 16);                   // truncation: residual exact
            const float fl = av[e] - __uint_as_float(u & 0xffff0000u);
            alo[kk][e] = (short)(__float_as_uint(fl) >> 16);
        }
    }

    // ---- MFMA main: 16 n-tiles x 4 k-steps x 2 passes = 128 MFMA/wave. ----
    f32x4 acc[16];
#pragma unroll
    for (int j = 0; j < 16; ++j) acc[j] = (f32x4){0.f, 0.f, 0.f, 0.f};

#pragma unroll
    for (int kk = 0; kk < 4; ++kk) {
        const int posr = ((32 * kk + 8 * g) + 8 * n15) & 127;
#pragma unroll
        for (int j = 0; j < 16; ++j) {
            const short8 bh = *reinterpret_cast<const short8*>(&phi[(16 * j + n15) * 128 + posr]);
            acc[j] = __builtin_amdgcn_mfma_f32_16x16x32_bf16(ahi[kk], bh, acc[j], 0, 0, 0);
            acc[j] = __builtin_amdgcn_mfma_f32_16x16x32_bf16(alo[kk], bh, acc[j], 0, 0, 0);
        }
    }

    // ---- rel[256] per row: lane partial over its 32 dims of row n15,
    //      xor16+xor32 combine g-groups -> lane l holds rel256 of row l&15. ----
    float rel_part = 0.f;
#pragma unroll
    for (int kk = 0; kk < 4; ++kk) {
        const short8 ph = *reinterpret_cast<const short8*>(&phi[256 * 128 + 32 * kk + 8 * g]);
#pragma unroll
        for (int e = 0; e < 8; ++e) {
            const float qv = __uint_as_float(((uint)(ushort)ahi[kk][e]) << 16)
                           + __uint_as_float(((uint)(ushort)alo[kk][e]) << 16);
            const float pv = __uint_as_float(((uint)(ushort)ph[e]) << 16);
            rel_part = fmaf(qv, pv, rel_part);
        }
    }
    rel_part += __shfl_xor(rel_part, 16, 64);
    rel_part += __shfl_xor(rel_part, 32, 64);

    // ---- epilogue: rows grouped by c = row&3 (4 rows per group, u = g slot).
    //      Spill reversed+shifted window (full-lane, conflict-free), pads,
    //      then 4 rows x 4 k-groups of {splat | one aligned b128 read} + store. ----
#pragma unroll
    for (int c = 0; c < 4; ++c) {
        // main spill: win[16j+n15] of row 4g+c -> rev[w][g][256 - (16j+n15) + c]
        // banks: (8g - n15) spread, max 2 lanes/bank (free).
#pragma unroll
        for (int j = 0; j < 16; ++j)
            rev[w][g][256 + c - 16 * j - n15] = acc[j][c];

        // pads + win[256]: lane (g, e=n15) serves sub-buffer u=g.
        {
            const float rel_r = __shfl(rel_part, 4 * g + c, 64);   // rel256 of row 4g+c
            const float r0_r  = __shfl(acc[0][c], 16 * g, 64);     // win[0]  of row 4g+c
            if (n15 <= 3) {
                if (n15 <= c) rev[w][g][n15] = rel_r;              // p in [0, c]
            } else if (n15 <= 10) {
                const int p = 253 + n15;                           // p in [257, 263]
                if (p >= 257 + c) rev[w][g][p] = r0_r;
            }
        }
        // DS pipe is in-order per wave and rev may-alias: the reads below
        // observe the writes above without an explicit drain.

#pragma unroll
        for (int u = 0; u < 4; ++u) {
            const int gRow = waveRow0 + 4 * u + c;
            const int t = gRow & (T_Q - 1);                        // t === c (mod 4)
            const int ofs = 128 - t + c;
            float* orow = out + (size_t)gRow * T_Q;
            const float rr256 = RL(rel_part, 4 * u + c);
            const float rr0   = RL(acc[0][c], 16 * u);

#pragma unroll
            for (int k = 0; k < 4; ++k) {
                const int s0 = 4 * l + 256 * k;
                const int j0 = t + 128 - s0;          // jraw at first component
                float4 v;
                if (j0 <= 0) {                         // all right-clipped -> win[0]
                    v = make_float4(rr0, rr0, rr0, rr0);
                } else if (j0 >= 259) {                // all left-clipped -> win[256]
                    v = make_float4(rr256, rr256, rr256, rr256);
                } else {                               // one aligned b128: p0 = s0+ofs
                    v = *reinterpret_cast<const float4*>(&rev[w][u][s0 + ofs]);
                }
                reinterpret_cast<float4*>(orow)[l + 64 * k] = v;   // fire-and-forget
            }
        }
        // next c's spill writes cannot pass this c's gather reads (DS in-order).
    }
}

extern "C" void kernel_launch(void* const* d_in, const int* in_sizes, int n_in,
                              void* d_out, int out_size, void* d_ws, size_t ws_size,
                              hipStream_t stream)
{
    const float* Q  = (const float*)d_in[0];
    // d_in[1] is K: only its shape matters (t_k = 1024), data unused.
    const float* pe = (const float*)d_in[2];
    float* out = (float*)d_out;

    const int total_rows = in_sizes[0] / D_DIM;        // m*h*t = 65536
    const int grid = total_rows / ROWS_PER_BLOCK;      // 256 -> one block per CU
    rpe_mfma<<<grid, BLOCK_THREADS, 0, stream>>>(Q, pe, out);
}

// Round 12
// 77.791 us; speedup vs baseline: 1.4478x; 1.0533x over previous
//
#include <hip/hip_runtime.h>

// Problem constants: m=4, h=16, t=1024, d=128, MAX_REL=128.
constexpr int D_DIM = 128;
constexpr int T_Q   = 1024;
constexpr int NPE   = 257;               // 2*MAX_REL + 1 pe rows
constexpr int WAVES = 8;                 // 512-thread block
constexpr int BLOCK_THREADS  = WAVES * 64;
constexpr int ROWS_PER_WAVE  = 16;       // one 16-row MFMA M-tile per wave
constexpr int ROWS_PER_BLOCK = WAVES * ROWS_PER_WAVE;   // 128; grid 512 -> 2 blocks/CU

typedef __attribute__((ext_vector_type(8))) short short8;  // bf16x8 MFMA operand
typedef __attribute__((ext_vector_type(4))) float f32x4;   // MFMA accumulator

// readlane: uniform lane index -> SGPR broadcast, no DS/memory.
#define RL(V, SRC) __uint_as_float(__builtin_amdgcn_readlane(__float_as_uint(V), (SRC)))

// Window GEMM per wave: D[16 rows][257 pe-rows] = Q_tile . pe^T, K=128.
// Precision: pe -> bf16 RNE; q -> hi + lo (truncation split), 2 MFMA passes.
// Layout contract (k-permutation-invariant): A row m = lane&15, B col n =
// lane&15, k-dims {32kk+8g+e} in matching slots. C/D (HW-verified m89):
// col = lane&15, row = (lane>>4)*4 + reg.
//
// LDS phases (UNION, 65.8 KB -> 2 blocks/CU):
//   phase 1 (staging .. rel256): phi = bf16 [257][128], rotated +8*(n&15)
//   phase 2 (epilogue, after __syncthreads): rev[8][4][264] f32 (33.8 KB)
// phi is dead once every wave finished its MFMA + rel256 reads; the barrier
// makes the overlay safe. Two blocks/CU de-phase compute vs store bursts.
//
// Epilogue (as r11): window stored REVERSED with shift c = row&3 into
// rev[u][p], pads for clip regions; out[s0..s0+3] = one aligned ds_read_b128.
__global__ __launch_bounds__(BLOCK_THREADS, 4)   // 4 waves/EU -> <=128 VGPR
void rpe_mfma(const float* __restrict__ Q,
              const float* __restrict__ pe,
              float* __restrict__ out)
{
    __shared__ char smem_raw[NPE * 128 * 2];     // 65792 B, overlaid phases
    ushort* phi = reinterpret_cast<ushort*>(smem_raw);
    float (*rev)[4][264] = reinterpret_cast<float(*)[4][264]>(smem_raw);

    const int tid = threadIdx.x;
    const int w   = tid >> 6;
    const int l   = tid & 63;
    const int n15 = l & 15;
    const int g   = l >> 4;

    // ---- stage pe -> phi as bf16 (RNE), rotated; vectorized: one float4
    //      read -> one ds_write_b64 of 4 bf16 (posr0 multiple of 4, no wrap). ----
    for (int q4 = tid; q4 < NPE * 32; q4 += BLOCK_THREADS) {
        const int n  = q4 >> 5;
        const int d0 = (q4 & 31) * 4;
        const float4 f = *reinterpret_cast<const float4*>(pe + n * 128 + d0);
        const float fv[4] = {f.x, f.y, f.z, f.w};
        ushort h[4];
#pragma unroll
        for (int e = 0; e < 4; ++e) {
            const uint u = __float_as_uint(fv[e]);
            h[e] = (ushort)((u + 0x7FFFu + ((u >> 16) & 1u)) >> 16);   // RNE
        }
        const int posr0 = (d0 + 8 * (n & 15)) & 127;
        *reinterpret_cast<uint2*>(&phi[n * 128 + posr0]) = *reinterpret_cast<uint2*>(h);
    }
    __syncthreads();

    const int waveRow0 = blockIdx.x * ROWS_PER_BLOCK + w * ROWS_PER_WAVE;

    // ---- A-fragments: lane holds row (waveRow0 + n15), dims 32kk+8g..+7. ----
    const float* qrow = Q + (size_t)(waveRow0 + n15) * D_DIM;
    short8 ahi[4], alo[4];
#pragma unroll
    for (int kk = 0; kk < 4; ++kk) {
        const int base = 32 * kk + 8 * g;
        const float4 a0 = *reinterpret_cast<const float4*>(qrow + base);
        const float4 a1 = *reinterpret_cast<const float4*>(qrow + base + 4);
        const float av[8] = {a0.x, a0.y, a0.z, a0.w, a1.x, a1.y, a1.z, a1.w};
#pragma unroll
        for (int e = 0; e < 8; ++e) {
            const uint u = __float_as_uint(av[e]);
            ahi[kk][e] = (short)(u >> 16);                   // truncation: residual exact
            const float fl = av[e] - __uint_as_float(u & 0xffff0000u);
            alo[kk][e] = (short)(__float_as_uint(fl) >> 16);
        }
    }

    // ---- MFMA main: 16 n-tiles x 4 k-steps x 2 passes = 128 MFMA/wave. ----
    f32x4 acc[16];
#pragma unroll
    for (int j = 0; j < 16; ++j) acc[j] = (f32x4){0.f, 0.f, 0.f, 0.f};

#pragma unroll
    for (int kk = 0; kk < 4; ++kk) {
        const int posr = ((32 * kk + 8 * g) + 8 * n15) & 127;
#pragma unroll
        for (int j = 0; j < 16; ++j) {
            const short8 bh = *reinterpret_cast<const short8*>(&phi[(16 * j + n15) * 128 + posr]);
            acc[j] = __builtin_amdgcn_mfma_f32_16x16x32_bf16(ahi[kk], bh, acc[j], 0, 0, 0);
            acc[j] = __builtin_amdgcn_mfma_f32_16x16x32_bf16(alo[kk], bh, acc[j], 0, 0, 0);
        }
    }

    // ---- rel[256] per row: lane partial over its 32 dims of row n15,
    //      xor16+xor32 combine g-groups -> lane l holds rel256 of row l&15. ----
    float rel_part = 0.f;
#pragma unroll
    for (int kk = 0; kk < 4; ++kk) {
        const short8 ph = *reinterpret_cast<const short8*>(&phi[256 * 128 + 32 * kk + 8 * g]);
#pragma unroll
        for (int e = 0; e < 8; ++e) {
            const float qv = __uint_as_float(((uint)(ushort)ahi[kk][e]) << 16)
                           + __uint_as_float(((uint)(ushort)alo[kk][e]) << 16);
            const float pv = __uint_as_float(((uint)(ushort)ph[e]) << 16);
            rel_part = fmaf(qv, pv, rel_part);
        }
    }
    rel_part += __shfl_xor(rel_part, 16, 64);
    rel_part += __shfl_xor(rel_part, 32, 64);

    // ---- phi is now dead in EVERY wave after this barrier: overlay rev. ----
    __syncthreads();

    // ---- epilogue: rows grouped by c = row&3 (4 rows per group, u slot = g).
    //      Spill reversed+shifted window (full-lane, conflict-free), pads,
    //      then 4 rows x 4 k-groups of {splat | one aligned b128 read} + store. ----
#pragma unroll
    for (int c = 0; c < 4; ++c) {
        // main spill: win[16j+n15] of row 4g+c -> rev[w][g][256 + c - 16j - n15]
#pragma unroll
        for (int j = 0; j < 16; ++j)
            rev[w][g][256 + c - 16 * j - n15] = acc[j][c];

        // pads + win[256]: lanes of group g serve sub-buffer u=g.
        {
            const float rel_r = __shfl(rel_part, 4 * g + c, 64);   // rel256 of row 4g+c
            const float r0_r  = __shfl(acc[0][c], 16 * g, 64);     // win[0]  of row 4g+c
            if (n15 <= 3) {
                if (n15 <= c) rev[w][g][n15] = rel_r;              // p in [0, c]
            } else if (n15 <= 10) {
                const int p = 253 + n15;                           // p in [257, 263]
                if (p >= 257 + c) rev[w][g][p] = r0_r;
            }
        }
        // DS in-order per wave + may-alias: reads below observe writes above.

#pragma unroll
        for (int u = 0; u < 4; ++u) {
            const int gRow = waveRow0 + 4 * u + c;
            const int t = gRow & (T_Q - 1);                        // t === c (mod 4)
            const int ofs = 128 - t + c;
            float* orow = out + (size_t)gRow * T_Q;
            const float rr256 = RL(rel_part, 4 * u + c);
            const float rr0   = RL(acc[0][c], 16 * u);

#pragma unroll
            for (int k = 0; k < 4; ++k) {
                const int s0 = 4 * l + 256 * k;
                const int j0 = t + 128 - s0;          // jraw at first component
                float4 v;
                if (j0 <= 0) {                         // all right-clipped -> win[0]
                    v = make_float4(rr0, rr0, rr0, rr0);
                } else if (j0 >= 259) {                // all left-clipped -> win[256]
                    v = make_float4(rr256, rr256, rr256, rr256);
                } else {                               // one aligned b128: p0 = s0+ofs
                    v = *reinterpret_cast<const float4*>(&rev[w][u][s0 + ofs]);
                }
                reinterpret_cast<float4*>(orow)[l + 64 * k] = v;   // fire-and-forget
            }
        }
        // next c's spill writes cannot pass this c's gather reads (DS in-order).
    }
}

extern "C" void kernel_launch(void* const* d_in, const int* in_sizes, int n_in,
                              void* d_out, int out_size, void* d_ws, size_t ws_size,
                              hipStream_t stream)
{
    const float* Q  = (const float*)d_in[0];
    // d_in[1] is K: only its shape matters (t_k = 1024), data unused.
    const float* pe = (const float*)d_in[2];
    float* out = (float*)d_out;

    const int total_rows = in_sizes[0] / D_DIM;        // m*h*t = 65536
    const int grid = total_rows / ROWS_PER_BLOCK;      // 512 -> 2 blocks/CU
    rpe_mfma<<<grid, BLOCK_THREADS, 0, stream>>>(Q, pe, out);
}